// Round 11
// baseline (388.859 us; speedup 1.0000x reference)
//
#include <hip/hip_runtime.h>
#include <cstdint>
#include <cstddef>

// MultiHeadSelfAttention: B=4 H=16 S=2048 D=1024 d=64
// d_out = [output fp32 (4,2048,1024)] ++ [attn_weights fp32 (4,16,2048,2048)]
//
// R11: attn QBLK 128->256 (8 waves x 32 q-rows). Halves pass-A total work and
//      K/V re-fetch (8 blocks/head instead of 16). NT stores kept (R10's +80us
//      win). GEMMs/cvt unchanged.

#define D_MODEL 1024
#define NHEADS  16
#define HDIM    64
#define BATCH   4
#define SEQ     2048
#define NTOK    (BATCH*SEQ)   // 8192

typedef __bf16 bf16x8 __attribute__((ext_vector_type(8)));
typedef float  f32x4  __attribute__((ext_vector_type(4)));
typedef unsigned short u16x8 __attribute__((ext_vector_type(8)));

__device__ __forceinline__ uint16_t f2bf(float f) {
  union { float f; uint32_t u; } v; v.f = f;
  return (uint16_t)((v.u + 0x7FFFu + ((v.u >> 16) & 1u)) >> 16);
}
__device__ __forceinline__ float bf2f(uint16_t u) {
  union { uint32_t u; float f; } v; v.u = (uint32_t)u << 16; return v.f;
}
__device__ __forceinline__ bf16x8 ldbf8(const uint16_t* p) {
  return __builtin_bit_cast(bf16x8, *(const u16x8*)p);
}
__device__ __forceinline__ void nt_store4(float* p, float a, float b, float c, float d) {
  f32x4 v = { a, b, c, d };
  __builtin_nontemporal_store(v, (f32x4*)p);
}
#define MFMA16(a, b, c) __builtin_amdgcn_mfma_f32_16x16x32_bf16((a), (b), (c), 0, 0, 0)

// async global->LDS, 16B/lane; LDS dest = wave-uniform base + lane*16.
__device__ __forceinline__ void gl_lds16(const uint16_t* g, uint16_t* l) {
  __builtin_amdgcn_global_load_lds(
      (const __attribute__((address_space(1))) uint32_t*)g,
      (__attribute__((address_space(3))) uint32_t*)l, 16, 0, 0);
}

// ---------------- fp32 -> bf16 converts ----------------
__global__ __launch_bounds__(256) void cvt_kernel(const float* __restrict__ src,
                                                  uint16_t* __restrict__ dst, int n4) {
  int i = blockIdx.x * blockDim.x + threadIdx.x;
  if (i < n4) {
    float4 f = ((const float4*)src)[i];
    ushort4 o;
    o.x = f2bf(f.x); o.y = f2bf(f.y); o.z = f2bf(f.z); o.w = f2bf(f.w);
    ((ushort4*)dst)[i] = o;
  }
}
// all 4 weight matrices -> contiguous bf16 dst (wq|wk|wv|wo), one launch
__global__ __launch_bounds__(256)
void cvt_w_kernel(const float* __restrict__ wq, const float* __restrict__ wk,
                  const float* __restrict__ wv, const float* __restrict__ wo,
                  uint16_t* __restrict__ dst) {
  int i = blockIdx.x * blockDim.x + threadIdx.x;   // [0, 4*262144)
  int sel = i >> 18, off = i & 262143;
  const float* src = (sel == 0) ? wq : (sel == 1) ? wk : (sel == 2) ? wv : wo;
  float4 f = ((const float4*)src)[off];
  ushort4 o;
  o.x = f2bf(f.x); o.y = f2bf(f.y); o.z = f2bf(f.z); o.w = f2bf(f.w);
  ((ushort4*)dst)[i] = o;
}

// ---------------- fused QKV GEMM ----------------
// A[8192,1024] bf16; Wqkv[3072,1024] bf16 (rows: wq | wk | wv).
// seg 0 -> Qb bf16 [tok,1024]; seg 1 -> Kc bf16; seg 2 -> Vt bf16 [(b,h,d),s].
__global__ __launch_bounds__(256)
void gemm_qkv(const uint16_t* __restrict__ A, const uint16_t* __restrict__ Wqkv,
              const float* __restrict__ bq, const float* __restrict__ bk,
              const float* __restrict__ bv,
              uint16_t* __restrict__ Qb, uint16_t* __restrict__ Kc,
              uint16_t* __restrict__ Vt) {
  __shared__ uint16_t As[128 * 64];
  __shared__ uint16_t Bs[128 * 64];
  const int flat = blockIdx.x;                 // 1536 blocks
  const int l = (flat & 7) * 192 + (flat >> 3);
  const int bx = l % 24, by = l / 24;
  const int tid  = threadIdx.x;
  const int lane = tid & 63;
  const int wave = tid >> 6;
  const int wr = wave >> 1, wc = wave & 1;
  const int m0 = by * 128, n0 = bx * 128;
  const int lrow = lane & 15;
  const int grp  = lane >> 4;
  const int l8   = lane >> 3;
  const int c8   = lane & 7;

  f32x4 acc[4][4] = {};

  for (int k0 = 0; k0 < 1024; k0 += 64) {
#pragma unroll
    for (int it = 0; it < 4; ++it) {
      const int chunk = wave * 4 + it;
      const int row = chunk * 8 + l8;
      gl_lds16(&A   [(size_t)(m0 + row) * 1024 + k0 + c8 * 8], &As[chunk * 512]);
      gl_lds16(&Wqkv[(size_t)(n0 + row) * 1024 + k0 + c8 * 8], &Bs[chunk * 512]);
    }
    __syncthreads();
#pragma unroll
    for (int ks = 0; ks < 2; ++ks) {
      bf16x8 af[4], bfr[4];
#pragma unroll
      for (int i = 0; i < 4; ++i) {
        af [i] = ldbf8(&As[(wr * 64 + i * 16 + lrow) * 64 + ks * 32 + grp * 8]);
        bfr[i] = ldbf8(&Bs[(wc * 64 + i * 16 + lrow) * 64 + ks * 32 + grp * 8]);
      }
#pragma unroll
      for (int i = 0; i < 4; ++i)
#pragma unroll
        for (int j = 0; j < 4; ++j)
          acc[i][j] = MFMA16(af[i], bfr[j], acc[i][j]);
    }
    __syncthreads();
  }

  const int seg = n0 >> 10;                    // uniform per block
  const float* bp = (seg == 0) ? bq : (seg == 1) ? bk : bv;
  uint16_t* dst01 = (seg == 0) ? Qb : Kc;
  const int r0 = grp * 4;
#pragma unroll
  for (int i = 0; i < 4; ++i) {
#pragma unroll
    for (int j = 0; j < 4; ++j) {
      int gmb = m0 + wr * 64 + i * 16 + r0;
      int gn  = n0 + wc * 64 + j * 16 + lrow;
      int nloc = gn & 1023;
      float bv_ = bp[nloc];
#pragma unroll
      for (int r = 0; r < 4; ++r) {
        float v = acc[i][j][r] + bv_;
        int gm = gmb + r;
        if (seg < 2) {
          dst01[(size_t)gm * 1024 + nloc] = f2bf(v);
        } else {
          int b = gm >> 11, s = gm & (SEQ - 1);
          int h = nloc >> 6, d = nloc & (HDIM - 1);
          Vt[(((size_t)(b * NHEADS + h) * HDIM + d) << 11) + s] = f2bf(v);
        }
      }
    }
  }
}

// ---------------- out-proj GEMM (fp32 out, non-temporal) ----------------
__global__ __launch_bounds__(256)
void gemm_out(const uint16_t* __restrict__ A, const uint16_t* __restrict__ Bt,
              const float* __restrict__ bias, float* __restrict__ out) {
  __shared__ uint16_t As[128 * 64];
  __shared__ uint16_t Bs[128 * 64];
  const int flat = blockIdx.x;                 // 512 blocks
  const int l = (flat & 7) * 64 + (flat >> 3);
  const int bx = l & 7, by = l >> 3;
  const int tid  = threadIdx.x;
  const int lane = tid & 63;
  const int wave = tid >> 6;
  const int wr = wave >> 1, wc = wave & 1;
  const int m0 = by * 128, n0 = bx * 128;
  const int lrow = lane & 15;
  const int grp  = lane >> 4;
  const int l8   = lane >> 3;
  const int c8   = lane & 7;

  f32x4 acc[4][4] = {};

  for (int k0 = 0; k0 < 1024; k0 += 64) {
#pragma unroll
    for (int it = 0; it < 4; ++it) {
      const int chunk = wave * 4 + it;
      const int row = chunk * 8 + l8;
      gl_lds16(&A [(size_t)(m0 + row) * 1024 + k0 + c8 * 8], &As[chunk * 512]);
      gl_lds16(&Bt[(size_t)(n0 + row) * 1024 + k0 + c8 * 8], &Bs[chunk * 512]);
    }
    __syncthreads();
#pragma unroll
    for (int ks = 0; ks < 2; ++ks) {
      bf16x8 af[4], bfr[4];
#pragma unroll
      for (int i = 0; i < 4; ++i) {
        af [i] = ldbf8(&As[(wr * 64 + i * 16 + lrow) * 64 + ks * 32 + grp * 8]);
        bfr[i] = ldbf8(&Bs[(wc * 64 + i * 16 + lrow) * 64 + ks * 32 + grp * 8]);
      }
#pragma unroll
      for (int i = 0; i < 4; ++i)
#pragma unroll
        for (int j = 0; j < 4; ++j)
          acc[i][j] = MFMA16(af[i], bfr[j], acc[i][j]);
    }
    __syncthreads();
  }

  const int r0 = grp * 4;
#pragma unroll
  for (int i = 0; i < 4; ++i) {
#pragma unroll
    for (int j = 0; j < 4; ++j) {
      int gmb = m0 + wr * 64 + i * 16 + r0;
      int gn  = n0 + wc * 64 + j * 16 + lrow;
      float bv = bias[gn];
#pragma unroll
      for (int r = 0; r < 4; ++r)
        __builtin_nontemporal_store(acc[i][j][r] + bv,
                                    &out[(size_t)(gmb + r) * 1024 + gn]);
    }
  }
}

// ---------------- Attention (QBLK=256: 8 waves x 32 q-rows) ----------------
// LDS tile: element (row, colblk c) at lds[row*64 + (c ^ (row&7))*8]
__device__ __forceinline__ bf16x8 rd_tile(const uint16_t* t, int r, int s) {
  return ldbf8(&t[r * 64 + ((s ^ (r & 7)) * 8)]);
}

#define QBLK 256
// 1D grid 512 (XCD-swizzled, qt fastest: 8 consecutive blocks share a head's
// K/V = 512KB, L2-resident). 512 thr = 8 waves; wave owns 32 q rows (2 groups
// of 16). mfma(K,Q): lane holds scores for q=lane&15, k_loc=(lane>>4)*4+r.
__global__ __launch_bounds__(512)
void attn_kernel(const uint16_t* __restrict__ Q, const uint16_t* __restrict__ Kb,
                 const uint16_t* __restrict__ Vt, float* __restrict__ attnw,
                 uint16_t* __restrict__ ctx) {
  __shared__ uint16_t Ks[2][64 * 64];
  __shared__ uint16_t Vs[2][64 * 64];
  __shared__ uint16_t Pl[8][32 * 72];     // per-wave P: 32 q x 64 k (pad 8)
  const int tid  = threadIdx.x;
  const int lane = tid & 63;
  const int wave = tid >> 6;          // 0..7
  const int flat = blockIdx.x;        // 512 blocks
  const int lb = (flat & 7) * 64 + (flat >> 3);   // 64 consecutive per XCD
  const int qt = lb & 7, h = (lb >> 3) & 15, b = lb >> 7;
  const int q0 = qt * QBLK + wave * 32;
  const int lrow = lane & 15;
  const int grp  = lane >> 4;
  const float c = 0.125f * 1.44269504088896f;  // (1/sqrt(64)) * log2(e)

  const uint16_t* Kh = Kb + (size_t)(b * SEQ) * D_MODEL + h * HDIM;   // [s][d] str 1024
  const uint16_t* Vh = Vt + ((size_t)(b * NHEADS + h) * HDIM) * SEQ;  // [d][s] str 2048

  // Q fragments for both 16-row groups
  bf16x8 qf[2][2];
#pragma unroll
  for (int g = 0; g < 2; ++g) {
    const size_t qb = ((size_t)(b * SEQ) + q0 + g * 16 + lrow) * D_MODEL + h * HDIM;
    qf[g][0] = ldbf8(&Q[qb + grp * 8]);
    qf[g][1] = ldbf8(&Q[qb + 32 + grp * 8]);
  }

  // staging coords: wave stages rows [wave*8, wave*8+8) of each 64x64 tile
  const int srow = wave * 8 + (lane >> 3);
  const int scb  = (lane & 7) ^ (srow & 7);        // pre-swizzled source col-blk

  // ---- pass A: online max+sum per group; K double-buffered ----
  float m[2] = { -INFINITY, -INFINITY }, l[2] = { 0.f, 0.f };
  gl_lds16(&Kh[(size_t)srow * D_MODEL + scb * 8], &Ks[0][wave * 512]);
#pragma unroll 1
  for (int kc = 0; kc < SEQ / 64; ++kc) {
    const int cur = kc & 1;
    __syncthreads();
    if (kc + 1 < SEQ / 64)
      gl_lds16(&Kh[(size_t)((kc + 1) * 64 + srow) * D_MODEL + scb * 8],
               &Ks[cur ^ 1][wave * 512]);
    const uint16_t* kt_ = Ks[cur];
#pragma unroll
    for (int g = 0; g < 2; ++g) {
      f32x4 s[4];
#pragma unroll
      for (int kt = 0; kt < 4; ++kt) {
        f32x4 a = {};
        a = MFMA16(rd_tile(kt_, kt * 16 + lrow, grp),     qf[g][0], a);
        a = MFMA16(rd_tile(kt_, kt * 16 + lrow, 4 + grp), qf[g][1], a);
        s[kt] = a;
      }
      float v[16];
#pragma unroll
      for (int kt = 0; kt < 4; ++kt)
#pragma unroll
        for (int r = 0; r < 4; ++r) v[kt * 4 + r] = s[kt][r] * c;
      float mx = v[0];
#pragma unroll
      for (int i = 1; i < 16; ++i) mx = fmaxf(mx, v[i]);
      float mn = fmaxf(m[g], mx);
      float sum = 0.f;
#pragma unroll
      for (int i = 0; i < 16; ++i) sum += __builtin_amdgcn_exp2f(v[i] - mn);
      l[g] = l[g] * __builtin_amdgcn_exp2f(m[g] - mn) + sum;
      m[g] = mn;
    }
  }
  float rinv[2];
#pragma unroll
  for (int g = 0; g < 2; ++g) {
#pragma unroll
    for (int d = 16; d <= 32; d <<= 1) {
      float mp = __shfl_xor(m[g], d), lp = __shfl_xor(l[g], d);
      float mn = fmaxf(m[g], mp);
      l[g] = l[g] * __builtin_amdgcn_exp2f(m[g] - mn) + lp * __builtin_amdgcn_exp2f(mp - mn);
      m[g] = mn;
    }
    rinv[g] = 1.0f / l[g];
  }

  // ---- pass B: recompute scores, weights + PV; K+V double-buffered ----
  f32x4 cacc[2][4] = {};
  uint16_t* pw = &Pl[wave][0];
  float* awc = attnw + (((size_t)(b * NHEADS + h)) * SEQ + q0) * SEQ;
  gl_lds16(&Kh[(size_t)srow * D_MODEL + scb * 8], &Ks[0][wave * 512]);
  gl_lds16(&Vh[(size_t)srow * SEQ + scb * 8],     &Vs[0][wave * 512]);
#pragma unroll 1
  for (int kc = 0; kc < SEQ / 64; ++kc) {
    const int cur = kc & 1;
    __syncthreads();
    if (kc + 1 < SEQ / 64) {
      gl_lds16(&Kh[(size_t)((kc + 1) * 64 + srow) * D_MODEL + scb * 8],
               &Ks[cur ^ 1][wave * 512]);
      gl_lds16(&Vh[(size_t)srow * SEQ + (kc + 1) * 64 + scb * 8],
               &Vs[cur ^ 1][wave * 512]);
    }
    const uint16_t* kt_ = Ks[cur];
#pragma unroll
    for (int g = 0; g < 2; ++g) {
      f32x4 s[4];
#pragma unroll
      for (int kt = 0; kt < 4; ++kt) {
        f32x4 a = {};
        a = MFMA16(rd_tile(kt_, kt * 16 + lrow, grp),     qf[g][0], a);
        a = MFMA16(rd_tile(kt_, kt * 16 + lrow, 4 + grp), qf[g][1], a);
        s[kt] = a;
      }
#pragma unroll
      for (int kt = 0; kt < 4; ++kt) {
        ushort4 w;
        w.x = f2bf(__builtin_amdgcn_exp2f(s[kt][0] * c - m[g]) * rinv[g]);
        w.y = f2bf(__builtin_amdgcn_exp2f(s[kt][1] * c - m[g]) * rinv[g]);
        w.z = f2bf(__builtin_amdgcn_exp2f(s[kt][2] * c - m[g]) * rinv[g]);
        w.w = f2bf(__builtin_amdgcn_exp2f(s[kt][3] * c - m[g]) * rinv[g]);
        *(ushort4*)&pw[(g * 16 + lrow) * 72 + kt * 16 + grp * 4] = w;
      }
    }
    asm volatile("s_waitcnt lgkmcnt(0)" ::: "memory");
    // coalesced fp32 weight stores (non-temporal): 8 x (4 q-rows x 256B)
#pragma unroll
    for (int g = 0; g < 2; ++g)
#pragma unroll
      for (int ii = 0; ii < 4; ++ii) {
        int q = g * 16 + ii * 4 + grp;
        ushort4 t4 = *(const ushort4*)&pw[q * 72 + lrow * 4];
        nt_store4(&awc[(size_t)q * SEQ + kc * 64 + lrow * 4],
                  bf2f(t4.x), bf2f(t4.y), bf2f(t4.z), bf2f(t4.w));
      }
    // PV over this 64-key chunk
    const uint16_t* vt_ = Vs[cur];
#pragma unroll
    for (int ks = 0; ks < 2; ++ks) {
      bf16x8 pf0 = ldbf8(&pw[(lrow)      * 72 + ks * 32 + grp * 8]);
      bf16x8 pf1 = ldbf8(&pw[(16 + lrow) * 72 + ks * 32 + grp * 8]);
#pragma unroll
      for (int n = 0; n < 4; ++n) {
        const bf16x8 vf = rd_tile(vt_, n * 16 + lrow, ks * 4 + grp);
        cacc[0][n] = MFMA16(pf0, vf, cacc[0][n]);
        cacc[1][n] = MFMA16(pf1, vf, cacc[1][n]);
      }
    }
  }
  // ctx: lane holds ctx[q = g*16 + grp*4+r][d = n*16+lrow]
#pragma unroll
  for (int g = 0; g < 2; ++g)
#pragma unroll
    for (int n = 0; n < 4; ++n)
#pragma unroll
      for (int r = 0; r < 4; ++r) {
        int gq = q0 + g * 16 + grp * 4 + r;
        ctx[((size_t)(b * SEQ) + gq) * D_MODEL + h * HDIM + n * 16 + lrow] = f2bf(cacc[g][n][r]);
      }
}

// ---------------- launch ----------------
extern "C" void kernel_launch(void* const* d_in, const int* in_sizes, int n_in,
                              void* d_out, int out_size, void* d_ws, size_t ws_size,
                              hipStream_t stream) {
  const float* x  = (const float*)d_in[0];
  const float* wq = (const float*)d_in[1];
  const float* bq = (const float*)d_in[2];
  const float* wk = (const float*)d_in[3];
  const float* bk = (const float*)d_in[4];
  const float* wv = (const float*)d_in[5];
  const float* bv = (const float*)d_in[6];
  const float* wo = (const float*)d_in[7];
  const float* bo = (const float*)d_in[8];

  char* ws = (char*)d_ws;
  uint16_t* xb   = (uint16_t*)ws;                   // 16 MB (reused as ctx)
  uint16_t* wqkv = (uint16_t*)(ws + (16u << 20));   // 6 MB: wq|wk|wv rows
  uint16_t* wob  = (uint16_t*)(ws + (22u << 20));   // 2 MB (contiguous after wqkv)
  uint16_t* Qb   = (uint16_t*)(ws + (24u << 20));
  uint16_t* Kc   = (uint16_t*)(ws + (40u << 20));
  uint16_t* Vtb  = (uint16_t*)(ws + (56u << 20));
  uint16_t* ctx  = xb;

  float* outp  = (float*)d_out;
  float* attnw = outp + (size_t)NTOK * D_MODEL;

  {
    int n4 = (NTOK * D_MODEL) / 4;
    cvt_kernel<<<(n4 + 255) / 256, 256, 0, stream>>>(x, xb, n4);
    cvt_w_kernel<<<(4 * 262144) / 256, 256, 0, stream>>>(wq, wk, wv, wo, wqkv);
  }

  gemm_qkv<<<1536, 256, 0, stream>>>(xb, wqkv, bq, bk, bv, Qb, Kc, Vtb);

  attn_kernel<<<512, 512, 0, stream>>>(Qb, Kc, Vtb, attnw, ctx);

  gemm_out<<<512, 256, 0, stream>>>(ctx, wob, bo, outp);
}

// Round 12
// 384.886 us; speedup vs baseline: 1.0103x; 1.0103x over previous
//
#include <hip/hip_runtime.h>
#include <cstdint>
#include <cstddef>

// MultiHeadSelfAttention: B=4 H=16 S=2048 D=1024 d=64
// d_out = [output fp32 (4,2048,1024)] ++ [attn_weights fp32 (4,16,2048,2048)]
//
// R12 = R10 (QBLK=128, proven 388us) + two attn-only levers:
//   (1) no-max softmax: l = sum exp2(s*c) directly (scores*c in +-2, fp32
//       exact; R9 proved R8's accuracy failure was the staging, not no-max);
//   (2) s_setprio(1) around MFMA clusters (T5; blocks at different phases).

#define D_MODEL 1024
#define NHEADS  16
#define HDIM    64
#define BATCH   4
#define SEQ     2048
#define NTOK    (BATCH*SEQ)   // 8192

typedef __bf16 bf16x8 __attribute__((ext_vector_type(8)));
typedef float  f32x4  __attribute__((ext_vector_type(4)));
typedef unsigned short u16x8 __attribute__((ext_vector_type(8)));

__device__ __forceinline__ uint16_t f2bf(float f) {
  union { float f; uint32_t u; } v; v.f = f;
  return (uint16_t)((v.u + 0x7FFFu + ((v.u >> 16) & 1u)) >> 16);
}
__device__ __forceinline__ float bf2f(uint16_t u) {
  union { uint32_t u; float f; } v; v.u = (uint32_t)u << 16; return v.f;
}
__device__ __forceinline__ bf16x8 ldbf8(const uint16_t* p) {
  return __builtin_bit_cast(bf16x8, *(const u16x8*)p);
}
__device__ __forceinline__ void nt_store4(float* p, float a, float b, float c, float d) {
  f32x4 v = { a, b, c, d };
  __builtin_nontemporal_store(v, (f32x4*)p);
}
#define MFMA16(a, b, c) __builtin_amdgcn_mfma_f32_16x16x32_bf16((a), (b), (c), 0, 0, 0)

// async global->LDS, 16B/lane; LDS dest = wave-uniform base + lane*16.
__device__ __forceinline__ void gl_lds16(const uint16_t* g, uint16_t* l) {
  __builtin_amdgcn_global_load_lds(
      (const __attribute__((address_space(1))) uint32_t*)g,
      (__attribute__((address_space(3))) uint32_t*)l, 16, 0, 0);
}

// ---------------- fp32 -> bf16 converts ----------------
__global__ __launch_bounds__(256) void cvt_kernel(const float* __restrict__ src,
                                                  uint16_t* __restrict__ dst, int n4) {
  int i = blockIdx.x * blockDim.x + threadIdx.x;
  if (i < n4) {
    float4 f = ((const float4*)src)[i];
    ushort4 o;
    o.x = f2bf(f.x); o.y = f2bf(f.y); o.z = f2bf(f.z); o.w = f2bf(f.w);
    ((ushort4*)dst)[i] = o;
  }
}
// all 4 weight matrices -> contiguous bf16 dst (wq|wk|wv|wo), one launch
__global__ __launch_bounds__(256)
void cvt_w_kernel(const float* __restrict__ wq, const float* __restrict__ wk,
                  const float* __restrict__ wv, const float* __restrict__ wo,
                  uint16_t* __restrict__ dst) {
  int i = blockIdx.x * blockDim.x + threadIdx.x;   // [0, 4*262144)
  int sel = i >> 18, off = i & 262143;
  const float* src = (sel == 0) ? wq : (sel == 1) ? wk : (sel == 2) ? wv : wo;
  float4 f = ((const float4*)src)[off];
  ushort4 o;
  o.x = f2bf(f.x); o.y = f2bf(f.y); o.z = f2bf(f.z); o.w = f2bf(f.w);
  ((ushort4*)dst)[i] = o;
}

// ---------------- fused QKV GEMM ----------------
// A[8192,1024] bf16; Wqkv[3072,1024] bf16 (rows: wq | wk | wv).
// seg 0 -> Qb bf16 [tok,1024]; seg 1 -> Kc bf16; seg 2 -> Vt bf16 [(b,h,d),s].
__global__ __launch_bounds__(256)
void gemm_qkv(const uint16_t* __restrict__ A, const uint16_t* __restrict__ Wqkv,
              const float* __restrict__ bq, const float* __restrict__ bk,
              const float* __restrict__ bv,
              uint16_t* __restrict__ Qb, uint16_t* __restrict__ Kc,
              uint16_t* __restrict__ Vt) {
  __shared__ uint16_t As[128 * 64];
  __shared__ uint16_t Bs[128 * 64];
  const int flat = blockIdx.x;                 // 1536 blocks
  const int l = (flat & 7) * 192 + (flat >> 3);
  const int bx = l % 24, by = l / 24;
  const int tid  = threadIdx.x;
  const int lane = tid & 63;
  const int wave = tid >> 6;
  const int wr = wave >> 1, wc = wave & 1;
  const int m0 = by * 128, n0 = bx * 128;
  const int lrow = lane & 15;
  const int grp  = lane >> 4;
  const int l8   = lane >> 3;
  const int c8   = lane & 7;

  f32x4 acc[4][4] = {};

  for (int k0 = 0; k0 < 1024; k0 += 64) {
#pragma unroll
    for (int it = 0; it < 4; ++it) {
      const int chunk = wave * 4 + it;
      const int row = chunk * 8 + l8;
      gl_lds16(&A   [(size_t)(m0 + row) * 1024 + k0 + c8 * 8], &As[chunk * 512]);
      gl_lds16(&Wqkv[(size_t)(n0 + row) * 1024 + k0 + c8 * 8], &Bs[chunk * 512]);
    }
    __syncthreads();
#pragma unroll
    for (int ks = 0; ks < 2; ++ks) {
      bf16x8 af[4], bfr[4];
#pragma unroll
      for (int i = 0; i < 4; ++i) {
        af [i] = ldbf8(&As[(wr * 64 + i * 16 + lrow) * 64 + ks * 32 + grp * 8]);
        bfr[i] = ldbf8(&Bs[(wc * 64 + i * 16 + lrow) * 64 + ks * 32 + grp * 8]);
      }
#pragma unroll
      for (int i = 0; i < 4; ++i)
#pragma unroll
        for (int j = 0; j < 4; ++j)
          acc[i][j] = MFMA16(af[i], bfr[j], acc[i][j]);
    }
    __syncthreads();
  }

  const int seg = n0 >> 10;                    // uniform per block
  const float* bp = (seg == 0) ? bq : (seg == 1) ? bk : bv;
  uint16_t* dst01 = (seg == 0) ? Qb : Kc;
  const int r0 = grp * 4;
#pragma unroll
  for (int i = 0; i < 4; ++i) {
#pragma unroll
    for (int j = 0; j < 4; ++j) {
      int gmb = m0 + wr * 64 + i * 16 + r0;
      int gn  = n0 + wc * 64 + j * 16 + lrow;
      int nloc = gn & 1023;
      float bv_ = bp[nloc];
#pragma unroll
      for (int r = 0; r < 4; ++r) {
        float v = acc[i][j][r] + bv_;
        int gm = gmb + r;
        if (seg < 2) {
          dst01[(size_t)gm * 1024 + nloc] = f2bf(v);
        } else {
          int b = gm >> 11, s = gm & (SEQ - 1);
          int h = nloc >> 6, d = nloc & (HDIM - 1);
          Vt[(((size_t)(b * NHEADS + h) * HDIM + d) << 11) + s] = f2bf(v);
        }
      }
    }
  }
}

// ---------------- out-proj GEMM (fp32 out, non-temporal) ----------------
__global__ __launch_bounds__(256)
void gemm_out(const uint16_t* __restrict__ A, const uint16_t* __restrict__ Bt,
              const float* __restrict__ bias, float* __restrict__ out) {
  __shared__ uint16_t As[128 * 64];
  __shared__ uint16_t Bs[128 * 64];
  const int flat = blockIdx.x;                 // 512 blocks
  const int l = (flat & 7) * 64 + (flat >> 3);
  const int bx = l & 7, by = l >> 3;
  const int tid  = threadIdx.x;
  const int lane = tid & 63;
  const int wave = tid >> 6;
  const int wr = wave >> 1, wc = wave & 1;
  const int m0 = by * 128, n0 = bx * 128;
  const int lrow = lane & 15;
  const int grp  = lane >> 4;
  const int l8   = lane >> 3;
  const int c8   = lane & 7;

  f32x4 acc[4][4] = {};

  for (int k0 = 0; k0 < 1024; k0 += 64) {
#pragma unroll
    for (int it = 0; it < 4; ++it) {
      const int chunk = wave * 4 + it;
      const int row = chunk * 8 + l8;
      gl_lds16(&A [(size_t)(m0 + row) * 1024 + k0 + c8 * 8], &As[chunk * 512]);
      gl_lds16(&Bt[(size_t)(n0 + row) * 1024 + k0 + c8 * 8], &Bs[chunk * 512]);
    }
    __syncthreads();
#pragma unroll
    for (int ks = 0; ks < 2; ++ks) {
      bf16x8 af[4], bfr[4];
#pragma unroll
      for (int i = 0; i < 4; ++i) {
        af [i] = ldbf8(&As[(wr * 64 + i * 16 + lrow) * 64 + ks * 32 + grp * 8]);
        bfr[i] = ldbf8(&Bs[(wc * 64 + i * 16 + lrow) * 64 + ks * 32 + grp * 8]);
      }
#pragma unroll
      for (int i = 0; i < 4; ++i)
#pragma unroll
        for (int j = 0; j < 4; ++j)
          acc[i][j] = MFMA16(af[i], bfr[j], acc[i][j]);
    }
    __syncthreads();
  }

  const int r0 = grp * 4;
#pragma unroll
  for (int i = 0; i < 4; ++i) {
#pragma unroll
    for (int j = 0; j < 4; ++j) {
      int gmb = m0 + wr * 64 + i * 16 + r0;
      int gn  = n0 + wc * 64 + j * 16 + lrow;
      float bv = bias[gn];
#pragma unroll
      for (int r = 0; r < 4; ++r)
        __builtin_nontemporal_store(acc[i][j][r] + bv,
                                    &out[(size_t)(gmb + r) * 1024 + gn]);
    }
  }
}

// ---------------- Attention (R10 structure + no-max + setprio) ----------
// LDS tile: element (row, colblk c) at lds[row*64 + (c ^ (row&7))*8]
__device__ __forceinline__ bf16x8 rd_tile(const uint16_t* t, int r, int s) {
  return ldbf8(&t[r * 64 + ((s ^ (r & 7)) * 8)]);
}

#define QBLK 128
// 1D grid 1024 (XCD-swizzled), 512 thr = 8 waves; wave owns 16 q rows.
// mfma(K,Q): lane holds scores for q=lane&15, k_loc=(lane>>4)*4+r.
// No-max softmax: s*c (log2-domain) in +-~2, so l = sum exp2(s*c) is exact
// in fp32; softmax shift-invariance makes this identical to the max form.
__global__ __launch_bounds__(512)
void attn_kernel(const uint16_t* __restrict__ Q, const uint16_t* __restrict__ Kb,
                 const uint16_t* __restrict__ Vt, float* __restrict__ attnw,
                 uint16_t* __restrict__ ctx) {
  __shared__ uint16_t Ks[2][64 * 64];
  __shared__ uint16_t Vs[2][64 * 64];
  __shared__ uint16_t Pl[8][16 * 72];
  const int tid  = threadIdx.x;
  const int lane = tid & 63;
  const int wave = tid >> 6;          // 0..7
  const int flat = blockIdx.x;        // 1024 blocks
  const int lb = (flat & 7) * 128 + (flat >> 3);   // 128 consecutive per XCD
  const int qt = lb & 15, h = (lb >> 4) & 15, b = lb >> 8;
  const int q0 = qt * QBLK + wave * 16;
  const int lrow = lane & 15;
  const int grp  = lane >> 4;
  const float c = 0.125f * 1.44269504088896f;  // (1/sqrt(64)) * log2(e)

  const uint16_t* Kh = Kb + (size_t)(b * SEQ) * D_MODEL + h * HDIM;   // [s][d] str 1024
  const uint16_t* Vh = Vt + ((size_t)(b * NHEADS + h) * HDIM) * SEQ;  // [d][s] str 2048

  const size_t qbase = ((size_t)(b * SEQ) + q0 + lrow) * D_MODEL + h * HDIM;
  const bf16x8 qf0 = ldbf8(&Q[qbase + grp * 8]);
  const bf16x8 qf1 = ldbf8(&Q[qbase + 32 + grp * 8]);

  // staging coords: wave stages rows [wave*8, wave*8+8) of each 64x64 tile
  const int srow = wave * 8 + (lane >> 3);
  const int scb  = (lane & 7) ^ (srow & 7);        // pre-swizzled source col-blk

  // ---- pass A: sum of exp2; K double-buffered ----
  float l = 0.f;
  gl_lds16(&Kh[(size_t)srow * D_MODEL + scb * 8], &Ks[0][wave * 512]);
#pragma unroll 1
  for (int kc = 0; kc < SEQ / 64; ++kc) {
    const int cur = kc & 1;
    __syncthreads();   // cur staged across waves; prev readers of cur^1 done
    if (kc + 1 < SEQ / 64)
      gl_lds16(&Kh[(size_t)((kc + 1) * 64 + srow) * D_MODEL + scb * 8],
               &Ks[cur ^ 1][wave * 512]);
    const uint16_t* kt_ = Ks[cur];
    f32x4 s[4];
    __builtin_amdgcn_s_setprio(1);
#pragma unroll
    for (int kt = 0; kt < 4; ++kt) {
      f32x4 a = {};
      a = MFMA16(rd_tile(kt_, kt * 16 + lrow, grp),     qf0, a);
      a = MFMA16(rd_tile(kt_, kt * 16 + lrow, 4 + grp), qf1, a);
      s[kt] = a;
    }
    __builtin_amdgcn_s_setprio(0);
    float sum = 0.f;
#pragma unroll
    for (int kt = 0; kt < 4; ++kt)
#pragma unroll
      for (int r = 0; r < 4; ++r)
        sum += __builtin_amdgcn_exp2f(s[kt][r] * c);
    l += sum;
  }
  l += __shfl_xor(l, 16);
  l += __shfl_xor(l, 32);
  const float rinv = 1.0f / l;

  // ---- pass B: recompute scores, weights + PV; K+V double-buffered ----
  f32x4 cacc[4] = {};
  uint16_t* pw = &Pl[wave][0];
  float* awc = attnw + (((size_t)(b * NHEADS + h)) * SEQ + q0) * SEQ;
  gl_lds16(&Kh[(size_t)srow * D_MODEL + scb * 8], &Ks[0][wave * 512]);
  gl_lds16(&Vh[(size_t)srow * SEQ + scb * 8],     &Vs[0][wave * 512]);
#pragma unroll 1
  for (int kc = 0; kc < SEQ / 64; ++kc) {
    const int cur = kc & 1;
    __syncthreads();
    if (kc + 1 < SEQ / 64) {
      gl_lds16(&Kh[(size_t)((kc + 1) * 64 + srow) * D_MODEL + scb * 8],
               &Ks[cur ^ 1][wave * 512]);
      gl_lds16(&Vh[(size_t)srow * SEQ + (kc + 1) * 64 + scb * 8],
               &Vs[cur ^ 1][wave * 512]);
    }
    const uint16_t* kt_ = Ks[cur];
    f32x4 s[4];
    __builtin_amdgcn_s_setprio(1);
#pragma unroll
    for (int kt = 0; kt < 4; ++kt) {
      f32x4 a = {};
      a = MFMA16(rd_tile(kt_, kt * 16 + lrow, grp),     qf0, a);
      a = MFMA16(rd_tile(kt_, kt * 16 + lrow, 4 + grp), qf1, a);
      s[kt] = a;
    }
    __builtin_amdgcn_s_setprio(0);
#pragma unroll
    for (int kt = 0; kt < 4; ++kt) {
      ushort4 w;
      w.x = f2bf(__builtin_amdgcn_exp2f(s[kt][0] * c) * rinv);
      w.y = f2bf(__builtin_amdgcn_exp2f(s[kt][1] * c) * rinv);
      w.z = f2bf(__builtin_amdgcn_exp2f(s[kt][2] * c) * rinv);
      w.w = f2bf(__builtin_amdgcn_exp2f(s[kt][3] * c) * rinv);
      *(ushort4*)&pw[lrow * 72 + kt * 16 + grp * 4] = w;
    }
    asm volatile("s_waitcnt lgkmcnt(0)" ::: "memory");
    // coalesced fp32 weight stores (non-temporal): 4 x (4 q-rows x 256B)
#pragma unroll
    for (int ii = 0; ii < 4; ++ii) {
      int q = ii * 4 + grp;
      ushort4 t4 = *(const ushort4*)&pw[q * 72 + lrow * 4];
      nt_store4(&awc[(size_t)q * SEQ + kc * 64 + lrow * 4],
                bf2f(t4.x), bf2f(t4.y), bf2f(t4.z), bf2f(t4.w));
    }
    // PV over this 64-key chunk
    const uint16_t* vt_ = Vs[cur];
    __builtin_amdgcn_s_setprio(1);
#pragma unroll
    for (int ks = 0; ks < 2; ++ks) {
      const bf16x8 pf = ldbf8(&pw[lrow * 72 + ks * 32 + grp * 8]);
#pragma unroll
      for (int n = 0; n < 4; ++n) {
        const bf16x8 vf = rd_tile(vt_, n * 16 + lrow, ks * 4 + grp);
        cacc[n] = MFMA16(pf, vf, cacc[n]);
      }
    }
    __builtin_amdgcn_s_setprio(0);
  }
  // ctx: lane holds ctx[q = grp*4+r][d = n*16+lrow]
#pragma unroll
  for (int n = 0; n < 4; ++n)
#pragma unroll
    for (int r = 0; r < 4; ++r) {
      int gq = q0 + grp * 4 + r;
      ctx[((size_t)(b * SEQ) + gq) * D_MODEL + h * HDIM + n * 16 + lrow] = f2bf(cacc[n][r]);
    }
}

// ---------------- launch ----------------
extern "C" void kernel_launch(void* const* d_in, const int* in_sizes, int n_in,
                              void* d_out, int out_size, void* d_ws, size_t ws_size,
                              hipStream_t stream) {
  const float* x  = (const float*)d_in[0];
  const float* wq = (const float*)d_in[1];
  const float* bq = (const float*)d_in[2];
  const float* wk = (const float*)d_in[3];
  const float* bk = (const float*)d_in[4];
  const float* wv = (const float*)d_in[5];
  const float* bv = (const float*)d_in[6];
  const float* wo = (const float*)d_in[7];
  const float* bo = (const float*)d_in[8];

  char* ws = (char*)d_ws;
  uint16_t* xb   = (uint16_t*)ws;                   // 16 MB (reused as ctx)
  uint16_t* wqkv = (uint16_t*)(ws + (16u << 20));   // 6 MB: wq|wk|wv rows
  uint16_t* wob  = (uint16_t*)(ws + (22u << 20));   // 2 MB (contiguous after wqkv)
  uint16_t* Qb   = (uint16_t*)(ws + (24u << 20));
  uint16_t* Kc   = (uint16_t*)(ws + (40u << 20));
  uint16_t* Vtb  = (uint16_t*)(ws + (56u << 20));
  uint16_t* ctx  = xb;

  float* outp  = (float*)d_out;
  float* attnw = outp + (size_t)NTOK * D_MODEL;

  {
    int n4 = (NTOK * D_MODEL) / 4;
    cvt_kernel<<<(n4 + 255) / 256, 256, 0, stream>>>(x, xb, n4);
    cvt_w_kernel<<<(4 * 262144) / 256, 256, 0, stream>>>(wq, wk, wv, wo, wqkv);
  }

  gemm_qkv<<<1536, 256, 0, stream>>>(xb, wqkv, bq, bk, bv, Qb, Kc, Vtb);

  attn_kernel<<<1024, 512, 0, stream>>>(Qb, Kc, Vtb, attnw, ctx);

  gemm_out<<<512, 256, 0, stream>>>(ctx, wob, bo, outp);
}

// Round 13
// 367.068 us; speedup vs baseline: 1.0594x; 1.0485x over previous
//
#include <hip/hip_runtime.h>
#include <cstdint>
#include <cstddef>

// MultiHeadSelfAttention: B=4 H=16 S=2048 D=1024 d=64
// d_out = [output fp32 (4,2048,1024)] ++ [attn_weights fp32 (4,16,2048,2048)]
//
// R13 = R12 + packed V^T stores in gemm_qkv seg-2: the 4 acc r-values are 4
//       consecutive s (contiguous dim of V^T) -> one ushort4 8B store per
//       (i,j) instead of 4 scalar 2B stores at 4KB stride (4x fewer store
//       transactions). Everything else frozen.

#define D_MODEL 1024
#define NHEADS  16
#define HDIM    64
#define BATCH   4
#define SEQ     2048
#define NTOK    (BATCH*SEQ)   // 8192

typedef __bf16 bf16x8 __attribute__((ext_vector_type(8)));
typedef float  f32x4  __attribute__((ext_vector_type(4)));
typedef unsigned short u16x8 __attribute__((ext_vector_type(8)));

__device__ __forceinline__ uint16_t f2bf(float f) {
  union { float f; uint32_t u; } v; v.f = f;
  return (uint16_t)((v.u + 0x7FFFu + ((v.u >> 16) & 1u)) >> 16);
}
__device__ __forceinline__ float bf2f(uint16_t u) {
  union { uint32_t u; float f; } v; v.u = (uint32_t)u << 16; return v.f;
}
__device__ __forceinline__ bf16x8 ldbf8(const uint16_t* p) {
  return __builtin_bit_cast(bf16x8, *(const u16x8*)p);
}
__device__ __forceinline__ void nt_store4(float* p, float a, float b, float c, float d) {
  f32x4 v = { a, b, c, d };
  __builtin_nontemporal_store(v, (f32x4*)p);
}
#define MFMA16(a, b, c) __builtin_amdgcn_mfma_f32_16x16x32_bf16((a), (b), (c), 0, 0, 0)

// async global->LDS, 16B/lane; LDS dest = wave-uniform base + lane*16.
__device__ __forceinline__ void gl_lds16(const uint16_t* g, uint16_t* l) {
  __builtin_amdgcn_global_load_lds(
      (const __attribute__((address_space(1))) uint32_t*)g,
      (__attribute__((address_space(3))) uint32_t*)l, 16, 0, 0);
}

// ---------------- fp32 -> bf16 converts ----------------
__global__ __launch_bounds__(256) void cvt_kernel(const float* __restrict__ src,
                                                  uint16_t* __restrict__ dst, int n4) {
  int i = blockIdx.x * blockDim.x + threadIdx.x;
  if (i < n4) {
    float4 f = ((const float4*)src)[i];
    ushort4 o;
    o.x = f2bf(f.x); o.y = f2bf(f.y); o.z = f2bf(f.z); o.w = f2bf(f.w);
    ((ushort4*)dst)[i] = o;
  }
}
// all 4 weight matrices -> contiguous bf16 dst (wq|wk|wv|wo), one launch
__global__ __launch_bounds__(256)
void cvt_w_kernel(const float* __restrict__ wq, const float* __restrict__ wk,
                  const float* __restrict__ wv, const float* __restrict__ wo,
                  uint16_t* __restrict__ dst) {
  int i = blockIdx.x * blockDim.x + threadIdx.x;   // [0, 4*262144)
  int sel = i >> 18, off = i & 262143;
  const float* src = (sel == 0) ? wq : (sel == 1) ? wk : (sel == 2) ? wv : wo;
  float4 f = ((const float4*)src)[off];
  ushort4 o;
  o.x = f2bf(f.x); o.y = f2bf(f.y); o.z = f2bf(f.z); o.w = f2bf(f.w);
  ((ushort4*)dst)[i] = o;
}

// ---------------- fused QKV GEMM ----------------
// A[8192,1024] bf16; Wqkv[3072,1024] bf16 (rows: wq | wk | wv).
// seg 0 -> Qb bf16 [tok,1024]; seg 1 -> Kc bf16; seg 2 -> Vt bf16 [(b,h,d),s].
__global__ __launch_bounds__(256)
void gemm_qkv(const uint16_t* __restrict__ A, const uint16_t* __restrict__ Wqkv,
              const float* __restrict__ bq, const float* __restrict__ bk,
              const float* __restrict__ bv,
              uint16_t* __restrict__ Qb, uint16_t* __restrict__ Kc,
              uint16_t* __restrict__ Vt) {
  __shared__ uint16_t As[128 * 64];
  __shared__ uint16_t Bs[128 * 64];
  const int flat = blockIdx.x;                 // 1536 blocks
  const int l = (flat & 7) * 192 + (flat >> 3);
  const int bx = l % 24, by = l / 24;
  const int tid  = threadIdx.x;
  const int lane = tid & 63;
  const int wave = tid >> 6;
  const int wr = wave >> 1, wc = wave & 1;
  const int m0 = by * 128, n0 = bx * 128;
  const int lrow = lane & 15;
  const int grp  = lane >> 4;
  const int l8   = lane >> 3;
  const int c8   = lane & 7;

  f32x4 acc[4][4] = {};

  for (int k0 = 0; k0 < 1024; k0 += 64) {
#pragma unroll
    for (int it = 0; it < 4; ++it) {
      const int chunk = wave * 4 + it;
      const int row = chunk * 8 + l8;
      gl_lds16(&A   [(size_t)(m0 + row) * 1024 + k0 + c8 * 8], &As[chunk * 512]);
      gl_lds16(&Wqkv[(size_t)(n0 + row) * 1024 + k0 + c8 * 8], &Bs[chunk * 512]);
    }
    __syncthreads();
#pragma unroll
    for (int ks = 0; ks < 2; ++ks) {
      bf16x8 af[4], bfr[4];
#pragma unroll
      for (int i = 0; i < 4; ++i) {
        af [i] = ldbf8(&As[(wr * 64 + i * 16 + lrow) * 64 + ks * 32 + grp * 8]);
        bfr[i] = ldbf8(&Bs[(wc * 64 + i * 16 + lrow) * 64 + ks * 32 + grp * 8]);
      }
#pragma unroll
      for (int i = 0; i < 4; ++i)
#pragma unroll
        for (int j = 0; j < 4; ++j)
          acc[i][j] = MFMA16(af[i], bfr[j], acc[i][j]);
    }
    __syncthreads();
  }

  const int seg = n0 >> 10;                    // uniform per block
  const float* bp = (seg == 0) ? bq : (seg == 1) ? bk : bv;
  uint16_t* dst01 = (seg == 0) ? Qb : Kc;
  const int r0 = grp * 4;
#pragma unroll
  for (int i = 0; i < 4; ++i) {
#pragma unroll
    for (int j = 0; j < 4; ++j) {
      int gmb = m0 + wr * 64 + i * 16 + r0;
      int gn  = n0 + wc * 64 + j * 16 + lrow;
      int nloc = gn & 1023;
      float bv_ = bp[nloc];
      if (seg < 2) {
#pragma unroll
        for (int r = 0; r < 4; ++r)
          dst01[(size_t)(gmb + r) * 1024 + nloc] = f2bf(acc[i][j][r] + bv_);
      } else {
        // V^T: row (b,h,d) from gn; the 4 r-values are 4 CONSECUTIVE s
        // (s = gm & 2047) -> pack into one 8B ushort4 store.
        int b = gmb >> 11, s = gmb & (SEQ - 1);
        int h = nloc >> 6, d = nloc & (HDIM - 1);
        ushort4 w;
        w.x = f2bf(acc[i][j][0] + bv_);
        w.y = f2bf(acc[i][j][1] + bv_);
        w.z = f2bf(acc[i][j][2] + bv_);
        w.w = f2bf(acc[i][j][3] + bv_);
        *(ushort4*)&Vt[(((size_t)(b * NHEADS + h) * HDIM + d) << 11) + s] = w;
      }
    }
  }
}

// ---------------- out-proj GEMM (fp32 out, non-temporal) ----------------
__global__ __launch_bounds__(256)
void gemm_out(const uint16_t* __restrict__ A, const uint16_t* __restrict__ Bt,
              const float* __restrict__ bias, float* __restrict__ out) {
  __shared__ uint16_t As[128 * 64];
  __shared__ uint16_t Bs[128 * 64];
  const int flat = blockIdx.x;                 // 512 blocks
  const int l = (flat & 7) * 64 + (flat >> 3);
  const int bx = l & 7, by = l >> 3;
  const int tid  = threadIdx.x;
  const int lane = tid & 63;
  const int wave = tid >> 6;
  const int wr = wave >> 1, wc = wave & 1;
  const int m0 = by * 128, n0 = bx * 128;
  const int lrow = lane & 15;
  const int grp  = lane >> 4;
  const int l8   = lane >> 3;
  const int c8   = lane & 7;

  f32x4 acc[4][4] = {};

  for (int k0 = 0; k0 < 1024; k0 += 64) {
#pragma unroll
    for (int it = 0; it < 4; ++it) {
      const int chunk = wave * 4 + it;
      const int row = chunk * 8 + l8;
      gl_lds16(&A [(size_t)(m0 + row) * 1024 + k0 + c8 * 8], &As[chunk * 512]);
      gl_lds16(&Bt[(size_t)(n0 + row) * 1024 + k0 + c8 * 8], &Bs[chunk * 512]);
    }
    __syncthreads();
#pragma unroll
    for (int ks = 0; ks < 2; ++ks) {
      bf16x8 af[4], bfr[4];
#pragma unroll
      for (int i = 0; i < 4; ++i) {
        af [i] = ldbf8(&As[(wr * 64 + i * 16 + lrow) * 64 + ks * 32 + grp * 8]);
        bfr[i] = ldbf8(&Bs[(wc * 64 + i * 16 + lrow) * 64 + ks * 32 + grp * 8]);
      }
#pragma unroll
      for (int i = 0; i < 4; ++i)
#pragma unroll
        for (int j = 0; j < 4; ++j)
          acc[i][j] = MFMA16(af[i], bfr[j], acc[i][j]);
    }
    __syncthreads();
  }

  const int r0 = grp * 4;
#pragma unroll
  for (int i = 0; i < 4; ++i) {
#pragma unroll
    for (int j = 0; j < 4; ++j) {
      int gmb = m0 + wr * 64 + i * 16 + r0;
      int gn  = n0 + wc * 64 + j * 16 + lrow;
      float bv = bias[gn];
#pragma unroll
      for (int r = 0; r < 4; ++r)
        __builtin_nontemporal_store(acc[i][j][r] + bv,
                                    &out[(size_t)(gmb + r) * 1024 + gn]);
    }
  }
}

// ---------------- Attention (R12 structure, frozen) ----------
// LDS tile: element (row, colblk c) at lds[row*64 + (c ^ (row&7))*8]
__device__ __forceinline__ bf16x8 rd_tile(const uint16_t* t, int r, int s) {
  return ldbf8(&t[r * 64 + ((s ^ (r & 7)) * 8)]);
}

#define QBLK 128
// 1D grid 1024 (XCD-swizzled), 512 thr = 8 waves; wave owns 16 q rows.
// mfma(K,Q): lane holds scores for q=lane&15, k_loc=(lane>>4)*4+r.
// No-max softmax: s*c (log2-domain) in +-~2, so l = sum exp2(s*c) is exact
// in fp32; softmax shift-invariance makes this identical to the max form.
__global__ __launch_bounds__(512)
void attn_kernel(const uint16_t* __restrict__ Q, const uint16_t* __restrict__ Kb,
                 const uint16_t* __restrict__ Vt, float* __restrict__ attnw,
                 uint16_t* __restrict__ ctx) {
  __shared__ uint16_t Ks[2][64 * 64];
  __shared__ uint16_t Vs[2][64 * 64];
  __shared__ uint16_t Pl[8][16 * 72];
  const int tid  = threadIdx.x;
  const int lane = tid & 63;
  const int wave = tid >> 6;          // 0..7
  const int flat = blockIdx.x;        // 1024 blocks
  const int lb = (flat & 7) * 128 + (flat >> 3);   // 128 consecutive per XCD
  const int qt = lb & 15, h = (lb >> 4) & 15, b = lb >> 8;
  const int q0 = qt * QBLK + wave * 16;
  const int lrow = lane & 15;
  const int grp  = lane >> 4;
  const float c = 0.125f * 1.44269504088896f;  // (1/sqrt(64)) * log2(e)

  const uint16_t* Kh = Kb + (size_t)(b * SEQ) * D_MODEL + h * HDIM;   // [s][d] str 1024
  const uint16_t* Vh = Vt + ((size_t)(b * NHEADS + h) * HDIM) * SEQ;  // [d][s] str 2048

  const size_t qbase = ((size_t)(b * SEQ) + q0 + lrow) * D_MODEL + h * HDIM;
  const bf16x8 qf0 = ldbf8(&Q[qbase + grp * 8]);
  const bf16x8 qf1 = ldbf8(&Q[qbase + 32 + grp * 8]);

  // staging coords: wave stages rows [wave*8, wave*8+8) of each 64x64 tile
  const int srow = wave * 8 + (lane >> 3);
  const int scb  = (lane & 7) ^ (srow & 7);        // pre-swizzled source col-blk

  // ---- pass A: sum of exp2; K double-buffered ----
  float l = 0.f;
  gl_lds16(&Kh[(size_t)srow * D_MODEL + scb * 8], &Ks[0][wave * 512]);
#pragma unroll 1
  for (int kc = 0; kc < SEQ / 64; ++kc) {
    const int cur = kc & 1;
    __syncthreads();   // cur staged across waves; prev readers of cur^1 done
    if (kc + 1 < SEQ / 64)
      gl_lds16(&Kh[(size_t)((kc + 1) * 64 + srow) * D_MODEL + scb * 8],
               &Ks[cur ^ 1][wave * 512]);
    const uint16_t* kt_ = Ks[cur];
    f32x4 s[4];
    __builtin_amdgcn_s_setprio(1);
#pragma unroll
    for (int kt = 0; kt < 4; ++kt) {
      f32x4 a = {};
      a = MFMA16(rd_tile(kt_, kt * 16 + lrow, grp),     qf0, a);
      a = MFMA16(rd_tile(kt_, kt * 16 + lrow, 4 + grp), qf1, a);
      s[kt] = a;
    }
    __builtin_amdgcn_s_setprio(0);
    float sum = 0.f;
#pragma unroll
    for (int kt = 0; kt < 4; ++kt)
#pragma unroll
      for (int r = 0; r < 4; ++r)
        sum += __builtin_amdgcn_exp2f(s[kt][r] * c);
    l += sum;
  }
  l += __shfl_xor(l, 16);
  l += __shfl_xor(l, 32);
  const float rinv = 1.0f / l;

  // ---- pass B: recompute scores, weights + PV; K+V double-buffered ----
  f32x4 cacc[4] = {};
  uint16_t* pw = &Pl[wave][0];
  float* awc = attnw + (((size_t)(b * NHEADS + h)) * SEQ + q0) * SEQ;
  gl_lds16(&Kh[(size_t)srow * D_MODEL + scb * 8], &Ks[0][wave * 512]);
  gl_lds16(&Vh[(size_t)srow * SEQ + scb * 8],     &Vs[0][wave * 512]);
#pragma unroll 1
  for (int kc = 0; kc < SEQ / 64; ++kc) {
    const int cur = kc & 1;
    __syncthreads();
    if (kc + 1 < SEQ / 64) {
      gl_lds16(&Kh[(size_t)((kc + 1) * 64 + srow) * D_MODEL + scb * 8],
               &Ks[cur ^ 1][wave * 512]);
      gl_lds16(&Vh[(size_t)srow * SEQ + (kc + 1) * 64 + scb * 8],
               &Vs[cur ^ 1][wave * 512]);
    }
    const uint16_t* kt_ = Ks[cur];
    f32x4 s[4];
    __builtin_amdgcn_s_setprio(1);
#pragma unroll
    for (int kt = 0; kt < 4; ++kt) {
      f32x4 a = {};
      a = MFMA16(rd_tile(kt_, kt * 16 + lrow, grp),     qf0, a);
      a = MFMA16(rd_tile(kt_, kt * 16 + lrow, 4 + grp), qf1, a);
      s[kt] = a;
    }
    __builtin_amdgcn_s_setprio(0);
#pragma unroll
    for (int kt = 0; kt < 4; ++kt) {
      ushort4 w;
      w.x = f2bf(__builtin_amdgcn_exp2f(s[kt][0] * c) * rinv);
      w.y = f2bf(__builtin_amdgcn_exp2f(s[kt][1] * c) * rinv);
      w.z = f2bf(__builtin_amdgcn_exp2f(s[kt][2] * c) * rinv);
      w.w = f2bf(__builtin_amdgcn_exp2f(s[kt][3] * c) * rinv);
      *(ushort4*)&pw[lrow * 72 + kt * 16 + grp * 4] = w;
    }
    asm volatile("s_waitcnt lgkmcnt(0)" ::: "memory");
    // coalesced fp32 weight stores (non-temporal): 4 x (4 q-rows x 256B)
#pragma unroll
    for (int ii = 0; ii < 4; ++ii) {
      int q = ii * 4 + grp;
      ushort4 t4 = *(const ushort4*)&pw[q * 72 + lrow * 4];
      nt_store4(&awc[(size_t)q * SEQ + kc * 64 + lrow * 4],
                bf2f(t4.x), bf2f(t4.y), bf2f(t4.z), bf2f(t4.w));
    }
    // PV over this 64-key chunk
    const uint16_t* vt_ = Vs[cur];
    __builtin_amdgcn_s_setprio(1);
#pragma unroll
    for (int ks = 0; ks < 2; ++ks) {
      const bf16x8 pf = ldbf8(&pw[lrow * 72 + ks * 32 + grp * 8]);
#pragma unroll
      for (int n = 0; n < 4; ++n) {
        const bf16x8 vf = rd_tile(vt_, n * 16 + lrow, ks * 4 + grp);
        cacc[n] = MFMA16(pf, vf, cacc[n]);
      }
    }
    __builtin_amdgcn_s_setprio(0);
  }
  // ctx: lane holds ctx[q = grp*4+r][d = n*16+lrow]
#pragma unroll
  for (int n = 0; n < 4; ++n)
#pragma unroll
    for (int r = 0; r < 4; ++r) {
      int gq = q0 + grp * 4 + r;
      ctx[((size_t)(b * SEQ) + gq) * D_MODEL + h * HDIM + n * 16 + lrow] = f2bf(cacc[n][r]);
    }
}

// ---------------- launch ----------------
extern "C" void kernel_launch(void* const* d_in, const int* in_sizes, int n_in,
                              void* d_out, int out_size, void* d_ws, size_t ws_size,
                              hipStream_t stream) {
  const float* x  = (const float*)d_in[0];
  const float* wq = (const float*)d_in[1];
  const float* bq = (const float*)d_in[2];
  const float* wk = (const float*)d_in[3];
  const float* bk = (const float*)d_in[4];
  const float* wv = (const float*)d_in[5];
  const float* bv = (const float*)d_in[6];
  const float* wo = (const float*)d_in[7];
  const float* bo = (const float*)d_in[8];

  char* ws = (char*)d_ws;
  uint16_t* xb   = (uint16_t*)ws;                   // 16 MB (reused as ctx)
  uint16_t* wqkv = (uint16_t*)(ws + (16u << 20));   // 6 MB: wq|wk|wv rows
  uint16_t* wob  = (uint16_t*)(ws + (22u << 20));   // 2 MB (contiguous after wqkv)
  uint16_t* Qb   = (uint16_t*)(ws + (24u << 20));
  uint16_t* Kc   = (uint16_t*)(ws + (40u << 20));
  uint16_t* Vtb  = (uint16_t*)(ws + (56u << 20));
  uint16_t* ctx  = xb;

  float* outp  = (float*)d_out;
  float* attnw = outp + (size_t)NTOK * D_MODEL;

  {
    int n4 = (NTOK * D_MODEL) / 4;
    cvt_kernel<<<(n4 + 255) / 256, 256, 0, stream>>>(x, xb, n4);
    cvt_w_kernel<<<(4 * 262144) / 256, 256, 0, stream>>>(wq, wk, wv, wo, wqkv);
  }

  gemm_qkv<<<1536, 256, 0, stream>>>(xb, wqkv, bq, bk, bv, Qb, Kc, Vtb);

  attn_kernel<<<1024, 512, 0, stream>>>(Qb, Kc, Vtb, attnw, ctx);

  gemm_out<<<512, 256, 0, stream>>>(ctx, wob, bo, outp);
}

// Round 14
// 355.432 us; speedup vs baseline: 1.0940x; 1.0327x over previous
//
#include <hip/hip_runtime.h>
#include <cstdint>
#include <cstddef>

// MultiHeadSelfAttention: B=4 H=16 S=2048 D=1024 d=64
// d_out = [output fp32 (4,2048,1024)] ++ [attn_weights fp32 (4,16,2048,2048)]
//
// R14 = R13 with gemm_qkv rebuilt: 256x256 tile, BK=64, double-buffered LDS
//       (128KB), counted s_waitcnt vmcnt(8) at tile boundaries (never full
//       drain in steady state), XOR-swizzled LDS reads. attn/gemm_out/cvt
//       frozen from R13.

#define D_MODEL 1024
#define NHEADS  16
#define HDIM    64
#define BATCH   4
#define SEQ     2048
#define NTOK    (BATCH*SEQ)   // 8192

typedef __bf16 bf16x8 __attribute__((ext_vector_type(8)));
typedef float  f32x4  __attribute__((ext_vector_type(4)));
typedef unsigned short u16x8 __attribute__((ext_vector_type(8)));

__device__ __forceinline__ uint16_t f2bf(float f) {
  union { float f; uint32_t u; } v; v.f = f;
  return (uint16_t)((v.u + 0x7FFFu + ((v.u >> 16) & 1u)) >> 16);
}
__device__ __forceinline__ float bf2f(uint16_t u) {
  union { uint32_t u; float f; } v; v.u = (uint32_t)u << 16; return v.f;
}
__device__ __forceinline__ bf16x8 ldbf8(const uint16_t* p) {
  return __builtin_bit_cast(bf16x8, *(const u16x8*)p);
}
__device__ __forceinline__ void nt_store4(float* p, float a, float b, float c, float d) {
  f32x4 v = { a, b, c, d };
  __builtin_nontemporal_store(v, (f32x4*)p);
}
#define MFMA16(a, b, c) __builtin_amdgcn_mfma_f32_16x16x32_bf16((a), (b), (c), 0, 0, 0)

// async global->LDS, 16B/lane; LDS dest = wave-uniform base + lane*16.
__device__ __forceinline__ void gl_lds16(const uint16_t* g, uint16_t* l) {
  __builtin_amdgcn_global_load_lds(
      (const __attribute__((address_space(1))) uint32_t*)g,
      (__attribute__((address_space(3))) uint32_t*)l, 16, 0, 0);
}

// LDS tile read: element (row, colblk s) at t[row*64 + (s ^ (row&7))*8]
__device__ __forceinline__ bf16x8 rd_tile(const uint16_t* t, int r, int s) {
  return ldbf8(&t[r * 64 + ((s ^ (r & 7)) * 8)]);
}

// ---------------- fp32 -> bf16 converts ----------------
__global__ __launch_bounds__(256) void cvt_kernel(const float* __restrict__ src,
                                                  uint16_t* __restrict__ dst, int n4) {
  int i = blockIdx.x * blockDim.x + threadIdx.x;
  if (i < n4) {
    float4 f = ((const float4*)src)[i];
    ushort4 o;
    o.x = f2bf(f.x); o.y = f2bf(f.y); o.z = f2bf(f.z); o.w = f2bf(f.w);
    ((ushort4*)dst)[i] = o;
  }
}
__global__ __launch_bounds__(256)
void cvt_w_kernel(const float* __restrict__ wq, const float* __restrict__ wk,
                  const float* __restrict__ wv, const float* __restrict__ wo,
                  uint16_t* __restrict__ dst) {
  int i = blockIdx.x * blockDim.x + threadIdx.x;   // [0, 4*262144)
  int sel = i >> 18, off = i & 262143;
  const float* src = (sel == 0) ? wq : (sel == 1) ? wk : (sel == 2) ? wv : wo;
  float4 f = ((const float4*)src)[off];
  ushort4 o;
  o.x = f2bf(f.x); o.y = f2bf(f.y); o.z = f2bf(f.z); o.w = f2bf(f.w);
  ((ushort4*)dst)[i] = o;
}

// ---------------- fused QKV GEMM: 256x256, BK=64, counted-vmcnt dbuf -------
// A[8192,1024] bf16; Wqkv[3072,1024] bf16 (rows: wq | wk | wv).
// seg 0 -> Qb bf16 [tok,1024]; seg 1 -> Kc bf16; seg 2 -> Vt bf16 [(b,h,d),s].
// 512 thr = 8 waves (2 M x 4 N); per-wave output 128x64 (acc[8][4]).
// Per iter: barrier; stage tile t+1 (8 gl_lds/wave); vmcnt(8); barrier;
// compute tile t (24 ds_read_b128 + 64 MFMA). vmcnt(8) waits exactly for
// tile t's loads (FIFO) and leaves the 8 new prefetches in flight.
__global__ __launch_bounds__(512)
void gemm_qkv(const uint16_t* __restrict__ A, const uint16_t* __restrict__ Wqkv,
              const float* __restrict__ bq, const float* __restrict__ bk,
              const float* __restrict__ bv,
              uint16_t* __restrict__ Qb, uint16_t* __restrict__ Kc,
              uint16_t* __restrict__ Vt) {
  __shared__ uint16_t Abuf[2][256 * 64];   // 32KB each
  __shared__ uint16_t Bbuf[2][256 * 64];   // total 128KB
  const int tid  = threadIdx.x;
  const int lane = tid & 63;
  const int wave = tid >> 6;               // 0..7
  const int wm = wave >> 2, wn = wave & 3;
  const int flat = blockIdx.x;             // 384 blocks
  const int l = (flat & 7) * 48 + (flat >> 3);
  const int bx = l % 12, by = l / 12;
  const int m0 = by * 256, n0 = bx * 256;
  const int lrow = lane & 15;
  const int grp  = lane >> 4;
  const int sr8  = lane >> 3;              // 0..7 row-within-chunk
  const int sc   = lane & 7;               // source col-block (pre-XOR)

  f32x4 acc[8][4] = {};

  // stage one full K-tile (A + B) into buffer `buf`: 8 gl_lds per wave
  auto stageTile = [&](int t, int buf) {
    const int kof = t * 64;
#pragma unroll
    for (int h = 0; h < 2; ++h)
#pragma unroll
      for (int ch = 0; ch < 2; ++ch) {
        const int lr  = h * 128 + wave * 16 + ch * 8 + sr8;  // LDS row 0..255
        const int scb = sc ^ (lr & 7);
        const int dof = (h * 128 + wave * 16 + ch * 8) * 64; // wave-uniform
        gl_lds16(&A   [(size_t)(m0 + lr) * 1024 + kof + scb * 8], &Abuf[buf][dof]);
        gl_lds16(&Wqkv[(size_t)(n0 + lr) * 1024 + kof + scb * 8], &Bbuf[buf][dof]);
      }
  };

  stageTile(0, 0);
#pragma unroll 1
  for (int t = 0; t < 16; ++t) {
    const int c = t & 1;
    __builtin_amdgcn_s_barrier();          // all waves done reading buf c^1
    if (t + 1 < 16) {
      stageTile(t + 1, c ^ 1);
      asm volatile("s_waitcnt vmcnt(8)" ::: "memory");  // tile t landed
    } else {
      asm volatile("s_waitcnt vmcnt(0)" ::: "memory");
    }
    __builtin_amdgcn_s_barrier();          // buf c visible to all waves
    const uint16_t* Ab = &Abuf[c][0];
    const uint16_t* Bb = &Bbuf[c][0];
#pragma unroll
    for (int ks = 0; ks < 2; ++ks) {
      bf16x8 bfr[4];
#pragma unroll
      for (int j = 0; j < 4; ++j)
        bfr[j] = rd_tile(Bb, wn * 64 + j * 16 + lrow, ks * 4 + grp);
#pragma unroll
      for (int half = 0; half < 2; ++half) {
        bf16x8 af[4];
#pragma unroll
        for (int i = 0; i < 4; ++i)
          af[i] = rd_tile(Ab, wm * 128 + half * 64 + i * 16 + lrow, ks * 4 + grp);
#pragma unroll
        for (int i = 0; i < 4; ++i)
#pragma unroll
          for (int j = 0; j < 4; ++j)
            acc[half * 4 + i][j] = MFMA16(af[i], bfr[j], acc[half * 4 + i][j]);
      }
    }
  }

  // epilogue
  const int seg = n0 >> 10;                // uniform per block (bx/4)
  const float* bp = (seg == 0) ? bq : (seg == 1) ? bk : bv;
  uint16_t* dst01 = (seg == 0) ? Qb : Kc;
  const int r0 = grp * 4;
#pragma unroll
  for (int I = 0; I < 8; ++I) {
#pragma unroll
    for (int j = 0; j < 4; ++j) {
      int gmb = m0 + wm * 128 + I * 16 + r0;
      int gn  = n0 + wn * 64 + j * 16 + lrow;
      int nloc = gn & 1023;
      float bv_ = bp[nloc];
      if (seg < 2) {
#pragma unroll
        for (int r = 0; r < 4; ++r)
          dst01[(size_t)(gmb + r) * 1024 + nloc] = f2bf(acc[I][j][r] + bv_);
      } else {
        int b = gmb >> 11, s = gmb & (SEQ - 1);
        int h = nloc >> 6, d = nloc & (HDIM - 1);
        ushort4 w;
        w.x = f2bf(acc[I][j][0] + bv_);
        w.y = f2bf(acc[I][j][1] + bv_);
        w.z = f2bf(acc[I][j][2] + bv_);
        w.w = f2bf(acc[I][j][3] + bv_);
        *(ushort4*)&Vt[(((size_t)(b * NHEADS + h) * HDIM + d) << 11) + s] = w;
      }
    }
  }
}

// ---------------- out-proj GEMM (fp32 out, non-temporal; R13 structure) ----
__global__ __launch_bounds__(256)
void gemm_out(const uint16_t* __restrict__ A, const uint16_t* __restrict__ Bt,
              const float* __restrict__ bias, float* __restrict__ out) {
  __shared__ uint16_t As[128 * 64];
  __shared__ uint16_t Bs[128 * 64];
  const int flat = blockIdx.x;                 // 512 blocks
  const int l = (flat & 7) * 64 + (flat >> 3);
  const int bx = l & 7, by = l >> 3;
  const int tid  = threadIdx.x;
  const int lane = tid & 63;
  const int wave = tid >> 6;
  const int wr = wave >> 1, wc = wave & 1;
  const int m0 = by * 128, n0 = bx * 128;
  const int lrow = lane & 15;
  const int grp  = lane >> 4;
  const int l8   = lane >> 3;
  const int c8   = lane & 7;

  f32x4 acc[4][4] = {};

  for (int k0 = 0; k0 < 1024; k0 += 64) {
#pragma unroll
    for (int it = 0; it < 4; ++it) {
      const int chunk = wave * 4 + it;
      const int row = chunk * 8 + l8;
      gl_lds16(&A [(size_t)(m0 + row) * 1024 + k0 + c8 * 8], &As[chunk * 512]);
      gl_lds16(&Bt[(size_t)(n0 + row) * 1024 + k0 + c8 * 8], &Bs[chunk * 512]);
    }
    __syncthreads();
#pragma unroll
    for (int ks = 0; ks < 2; ++ks) {
      bf16x8 af[4], bfr[4];
#pragma unroll
      for (int i = 0; i < 4; ++i) {
        af [i] = ldbf8(&As[(wr * 64 + i * 16 + lrow) * 64 + ks * 32 + grp * 8]);
        bfr[i] = ldbf8(&Bs[(wc * 64 + i * 16 + lrow) * 64 + ks * 32 + grp * 8]);
      }
#pragma unroll
      for (int i = 0; i < 4; ++i)
#pragma unroll
        for (int j = 0; j < 4; ++j)
          acc[i][j] = MFMA16(af[i], bfr[j], acc[i][j]);
    }
    __syncthreads();
  }

  const int r0 = grp * 4;
#pragma unroll
  for (int i = 0; i < 4; ++i) {
#pragma unroll
    for (int j = 0; j < 4; ++j) {
      int gmb = m0 + wr * 64 + i * 16 + r0;
      int gn  = n0 + wc * 64 + j * 16 + lrow;
      float bv = bias[gn];
#pragma unroll
      for (int r = 0; r < 4; ++r)
        __builtin_nontemporal_store(acc[i][j][r] + bv,
                                    &out[(size_t)(gmb + r) * 1024 + gn]);
    }
  }
}

// ---------------- Attention (R13 structure, frozen) ----------
#define QBLK 128
__global__ __launch_bounds__(512)
void attn_kernel(const uint16_t* __restrict__ Q, const uint16_t* __restrict__ Kb,
                 const uint16_t* __restrict__ Vt, float* __restrict__ attnw,
                 uint16_t* __restrict__ ctx) {
  __shared__ uint16_t Ks[2][64 * 64];
  __shared__ uint16_t Vs[2][64 * 64];
  __shared__ uint16_t Pl[8][16 * 72];
  const int tid  = threadIdx.x;
  const int lane = tid & 63;
  const int wave = tid >> 6;          // 0..7
  const int flat = blockIdx.x;        // 1024 blocks
  const int lb = (flat & 7) * 128 + (flat >> 3);   // 128 consecutive per XCD
  const int qt = lb & 15, h = (lb >> 4) & 15, b = lb >> 8;
  const int q0 = qt * QBLK + wave * 16;
  const int lrow = lane & 15;
  const int grp  = lane >> 4;
  const float c = 0.125f * 1.44269504088896f;  // (1/sqrt(64)) * log2(e)

  const uint16_t* Kh = Kb + (size_t)(b * SEQ) * D_MODEL + h * HDIM;   // [s][d] str 1024
  const uint16_t* Vh = Vt + ((size_t)(b * NHEADS + h) * HDIM) * SEQ;  // [d][s] str 2048

  const size_t qbase = ((size_t)(b * SEQ) + q0 + lrow) * D_MODEL + h * HDIM;
  const bf16x8 qf0 = ldbf8(&Q[qbase + grp * 8]);
  const bf16x8 qf1 = ldbf8(&Q[qbase + 32 + grp * 8]);

  // staging coords: wave stages rows [wave*8, wave*8+8) of each 64x64 tile
  const int srow = wave * 8 + (lane >> 3);
  const int scb  = (lane & 7) ^ (srow & 7);        // pre-swizzled source col-blk

  // ---- pass A: sum of exp2; K double-buffered ----
  float l = 0.f;
  gl_lds16(&Kh[(size_t)srow * D_MODEL + scb * 8], &Ks[0][wave * 512]);
#pragma unroll 1
  for (int kc = 0; kc < SEQ / 64; ++kc) {
    const int cur = kc & 1;
    __syncthreads();   // cur staged across waves; prev readers of cur^1 done
    if (kc + 1 < SEQ / 64)
      gl_lds16(&Kh[(size_t)((kc + 1) * 64 + srow) * D_MODEL + scb * 8],
               &Ks[cur ^ 1][wave * 512]);
    const uint16_t* kt_ = Ks[cur];
    f32x4 s[4];
    __builtin_amdgcn_s_setprio(1);
#pragma unroll
    for (int kt = 0; kt < 4; ++kt) {
      f32x4 a = {};
      a = MFMA16(rd_tile(kt_, kt * 16 + lrow, grp),     qf0, a);
      a = MFMA16(rd_tile(kt_, kt * 16 + lrow, 4 + grp), qf1, a);
      s[kt] = a;
    }
    __builtin_amdgcn_s_setprio(0);
    float sum = 0.f;
#pragma unroll
    for (int kt = 0; kt < 4; ++kt)
#pragma unroll
      for (int r = 0; r < 4; ++r)
        sum += __builtin_amdgcn_exp2f(s[kt][r] * c);
    l += sum;
  }
  l += __shfl_xor(l, 16);
  l += __shfl_xor(l, 32);
  const float rinv = 1.0f / l;

  // ---- pass B: recompute scores, weights + PV; K+V double-buffered ----
  f32x4 cacc[4] = {};
  uint16_t* pw = &Pl[wave][0];
  float* awc = attnw + (((size_t)(b * NHEADS + h)) * SEQ + q0) * SEQ;
  gl_lds16(&Kh[(size_t)srow * D_MODEL + scb * 8], &Ks[0][wave * 512]);
  gl_lds16(&Vh[(size_t)srow * SEQ + scb * 8],     &Vs[0][wave * 512]);
#pragma unroll 1
  for (int kc = 0; kc < SEQ / 64; ++kc) {
    const int cur = kc & 1;
    __syncthreads();
    if (kc + 1 < SEQ / 64) {
      gl_lds16(&Kh[(size_t)((kc + 1) * 64 + srow) * D_MODEL + scb * 8],
               &Ks[cur ^ 1][wave * 512]);
      gl_lds16(&Vh[(size_t)srow * SEQ + (kc + 1) * 64 + scb * 8],
               &Vs[cur ^ 1][wave * 512]);
    }
    const uint16_t* kt_ = Ks[cur];
    f32x4 s[4];
    __builtin_amdgcn_s_setprio(1);
#pragma unroll
    for (int kt = 0; kt < 4; ++kt) {
      f32x4 a = {};
      a = MFMA16(rd_tile(kt_, kt * 16 + lrow, grp),     qf0, a);
      a = MFMA16(rd_tile(kt_, kt * 16 + lrow, 4 + grp), qf1, a);
      s[kt] = a;
    }
    __builtin_amdgcn_s_setprio(0);
#pragma unroll
    for (int kt = 0; kt < 4; ++kt) {
      ushort4 w;
      w.x = f2bf(__builtin_amdgcn_exp2f(s[kt][0] * c) * rinv);
      w.y = f2bf(__builtin_amdgcn_exp2f(s[kt][1] * c) * rinv);
      w.z = f2bf(__builtin_amdgcn_exp2f(s[kt][2] * c) * rinv);
      w.w = f2bf(__builtin_amdgcn_exp2f(s[kt][3] * c) * rinv);
      *(ushort4*)&pw[lrow * 72 + kt * 16 + grp * 4] = w;
    }
    asm volatile("s_waitcnt lgkmcnt(0)" ::: "memory");
#pragma unroll
    for (int ii = 0; ii < 4; ++ii) {
      int q = ii * 4 + grp;
      ushort4 t4 = *(const ushort4*)&pw[q * 72 + lrow * 4];
      nt_store4(&awc[(size_t)q * SEQ + kc * 64 + lrow * 4],
                bf2f(t4.x), bf2f(t4.y), bf2f(t4.z), bf2f(t4.w));
    }
    const uint16_t* vt_ = Vs[cur];
    __builtin_amdgcn_s_setprio(1);
#pragma unroll
    for (int ks = 0; ks < 2; ++ks) {
      const bf16x8 pf = ldbf8(&pw[lrow * 72 + ks * 32 + grp * 8]);
#pragma unroll
      for (int n = 0; n < 4; ++n) {
        const bf16x8 vf = rd_tile(vt_, n * 16 + lrow, ks * 4 + grp);
        cacc[n] = MFMA16(pf, vf, cacc[n]);
      }
    }
    __builtin_amdgcn_s_setprio(0);
  }
#pragma unroll
  for (int n = 0; n < 4; ++n)
#pragma unroll
    for (int r = 0; r < 4; ++r) {
      int gq = q0 + grp * 4 + r;
      ctx[((size_t)(b * SEQ) + gq) * D_MODEL + h * HDIM + n * 16 + lrow] = f2bf(cacc[n][r]);
    }
}

// ---------------- launch ----------------
extern "C" void kernel_launch(void* const* d_in, const int* in_sizes, int n_in,
                              void* d_out, int out_size, void* d_ws, size_t ws_size,
                              hipStream_t stream) {
  const float* x  = (const float*)d_in[0];
  const float* wq = (const float*)d_in[1];
  const float* bq = (const float*)d_in[2];
  const float* wk = (const float*)d_in[3];
  const float* bk = (const float*)d_in[4];
  const float* wv = (const float*)d_in[5];
  const float* bv = (const float*)d_in[6];
  const float* wo = (const float*)d_in[7];
  const float* bo = (const float*)d_in[8];

  char* ws = (char*)d_ws;
  uint16_t* xb   = (uint16_t*)ws;                   // 16 MB (reused as ctx)
  uint16_t* wqkv = (uint16_t*)(ws + (16u << 20));   // 6 MB: wq|wk|wv rows
  uint16_t* wob  = (uint16_t*)(ws + (22u << 20));   // 2 MB (contiguous after wqkv)
  uint16_t* Qb   = (uint16_t*)(ws + (24u << 20));
  uint16_t* Kc   = (uint16_t*)(ws + (40u << 20));
  uint16_t* Vtb  = (uint16_t*)(ws + (56u << 20));
  uint16_t* ctx  = xb;

  float* outp  = (float*)d_out;
  float* attnw = outp + (size_t)NTOK * D_MODEL;

  {
    int n4 = (NTOK * D_MODEL) / 4;
    cvt_kernel<<<(n4 + 255) / 256, 256, 0, stream>>>(x, xb, n4);
    cvt_w_kernel<<<(4 * 262144) / 256, 256, 0, stream>>>(wq, wk, wv, wo, wqkv);
  }

  gemm_qkv<<<384, 512, 0, stream>>>(xb, wqkv, bq, bk, bv, Qb, Kc, Vtb);

  attn_kernel<<<1024, 512, 0, stream>>>(Qb, Kc, Vtb, attnw, ctx);

  gemm_out<<<512, 256, 0, stream>>>(ctx, wob, bo, outp);
}